// Round 6
// baseline (759.808 us; speedup 1.0000x reference)
//
#include <hip/hip_runtime.h>
#include <hip/hip_bf16.h>
#include <stdint.h>

#define DIM 1024

typedef __attribute__((ext_vector_type(4))) float f32x4;
typedef __attribute__((ext_vector_type(8))) short short8;

__device__ __forceinline__ float bf2f(ushort u) {
    union { uint32_t u; float f; } c; c.u = ((uint32_t)u) << 16; return c.f;
}
__device__ __forceinline__ ushort f2bf(float f) {
    union { float f; uint32_t u; } c; c.f = f;
    uint32_t r = (c.u + 0x7fffu + ((c.u >> 16) & 1u)) >> 16;
    return (ushort)r;
}

// async global->LDS, 16B per lane. LDS dest is wave-uniform base (+lane*16 implicit).
__device__ __forceinline__ void async_copy16(void* lds, const void* g) {
    __builtin_amdgcn_global_load_lds((const __attribute__((address_space(1))) void*)g,
                                     (__attribute__((address_space(3))) void*)lds, 16, 0, 0);
}

// ---------------- small graph-prep kernels ----------------

__global__ void deg_kernel(const int* __restrict__ src, const int* __restrict__ dst,
                           int* out_deg, int* in_deg, int ee) {
    int e = blockIdx.x * 256 + threadIdx.x;
    if (e < ee) {
        atomicAdd(&out_deg[src[e]], 1);
        atomicAdd(&in_deg[dst[e]], 1);
    }
}

__global__ void norm_kernel(const int* __restrict__ out_deg, const int* __restrict__ in_deg,
                            float* ns, float* nd, int n) {
    int i = blockIdx.x * 256 + threadIdx.x;
    if (i < n) {
        int od = out_deg[i], id = in_deg[i];
        ns[i] = od > 0 ? rsqrtf((float)od) : 0.f;
        nd[i] = id > 0 ? rsqrtf((float)id) : 0.f;
    }
}

__global__ void csum_kernel(const int* __restrict__ src, const int* __restrict__ dst,
                            const float* __restrict__ nd, float* cw, int ee) {
    int e = blockIdx.x * 256 + threadIdx.x;
    if (e < ee) atomicAdd(&cw[src[e]], nd[dst[e]]);
}

// single-block shuffle-based exclusive scan of in_deg -> row_ptr + cursor (1024 threads)
__global__ void scan_kernel(const int* __restrict__ deg, int* row_ptr, int* cursor, int n) {
    __shared__ int wsum[16];
    __shared__ int carry_s;
    int tid = threadIdx.x, lane = tid & 63, wid = tid >> 6;
    if (tid == 0) carry_s = 0;
    __syncthreads();
    for (int base = 0; base < n; base += 1024) {
        int x = (base + tid < n) ? deg[base + tid] : 0;
        int v = x;
#pragma unroll
        for (int off = 1; off < 64; off <<= 1) {
            int u = __shfl_up(v, off);
            if (lane >= off) v += u;
        }
        if (lane == 63) wsum[wid] = v;
        __syncthreads();
        if (wid == 0 && lane < 16) {
            int wv = wsum[lane];
#pragma unroll
            for (int off = 1; off < 16; off <<= 1) {
                int wu = __shfl_up(wv, off);
                if (lane >= off) wv += wu;
            }
            wsum[lane] = wv;
        }
        __syncthreads();
        int waveoff = (wid > 0) ? wsum[wid - 1] : 0;
        if (base + tid < n) {
            int ex = carry_s + waveoff + v - x;
            row_ptr[base + tid] = ex;
            cursor[base + tid] = ex;
        }
        __syncthreads();
        if (tid == 0) carry_s += wsum[15];
        __syncthreads();
    }
}

__global__ void wnode_kernel(float* cw, const float* __restrict__ ns, int n) {
    int i = blockIdx.x * 256 + threadIdx.x;
    if (i < n) cw[i] *= ns[i];  // w_node = norm_src * c
}

__global__ void scatter_kernel(const int* __restrict__ src, const int* __restrict__ dst,
                               int* cursor, int* csr_src, int ee) {
    int e = blockIdx.x * 256 + threadIdx.x;
    if (e < ee) {
        int p = atomicAdd(&cursor[dst[e]], 1);
        csr_src[p] = src[e];
    }
}

// ---------------- pos MLP stage A: t = relu(clip(boxes) @ w_pos1 + b_pos1), bf16 ----------------
// one wave per row, grid-stride; lane owns 16 consecutive cols.

__global__ __launch_bounds__(256) void posA_kernel(const float* __restrict__ boxes,
                                                   const float* __restrict__ w1,
                                                   const float* __restrict__ b1,
                                                   ushort* __restrict__ t, int n) {
    int lane = threadIdx.x & 63, wid = threadIdx.x >> 6;
    int wave = blockIdx.x * 4 + wid, nw = gridDim.x * 4;
    int c0 = lane * 16;
    for (int row = wave; row < n; row += nw) {
        float b[4];
#pragma unroll
        for (int j = 0; j < 4; j++) {
            float v = boxes[row * 4 + j];
            b[j] = fminf(fmaxf(v, -10.f), 10.f);
        }
        short8 o[2];
#pragma unroll
        for (int h = 0; h < 2; h++) {
#pragma unroll
            for (int q = 0; q < 8; q++) {
                int col = c0 + h * 8 + q;
                float v = b1[col];
#pragma unroll
                for (int j = 0; j < 4; j++) v = fmaf(b[j], w1[j * DIM + col], v);
                o[h][q] = (short)f2bf(fmaxf(v, 0.f));
            }
        }
        *(short8*)(t + (size_t)row * DIM + c0) = o[0];
        *(short8*)(t + (size_t)row * DIM + c0 + 8) = o[1];
    }
}

// ---------------- weight transpose+convert: wt[n][k] = bf16(w[k][n]) ----------------

__global__ __launch_bounds__(256) void transpose_bf16_kernel(const float* __restrict__ w,
                                                             ushort* __restrict__ wt) {
    __shared__ float tile[32][33];
    int bx = blockIdx.x, by = blockIdx.y;
    int tx = threadIdx.x & 31, ty = threadIdx.x >> 5;  // 32x8
#pragma unroll
    for (int r = 0; r < 32; r += 8)
        tile[ty + r][tx] = w[(size_t)(by * 32 + ty + r) * DIM + bx * 32 + tx];
    __syncthreads();
#pragma unroll
    for (int r = 0; r < 32; r += 8)
        wt[(size_t)(bx * 32 + ty + r) * DIM + by * 32 + tx] = f2bf(tile[tx][ty + r]);
}

// ---------------- 256x128 bf16 MFMA GEMM, BK=32, 8 waves, 3 blocks/CU, counted-vmcnt dbuf ----
// Block intensity 87 FLOP/staged-byte (vs 64 at 128x128). Grid 632 = 8 XCD x 79, zero tail.
// EPI==0: outp = bf16(C)                                  (rows < mreal)
// EPI==1: outp = bf16((C + bias + feats) * nsrc[row])     (rows < mreal)

template <int EPI>
__global__ __launch_bounds__(512, 6) void gemm_kernel(
    const ushort* __restrict__ A, const ushort* __restrict__ Bt,
    const float* __restrict__ bias, const float* __restrict__ feats,
    const float* __restrict__ nsrc, ushort* __restrict__ outp,
    int mtiles, int mreal) {
    __shared__ __align__(128) ushort ldsA[2][256 * 32];
    __shared__ __align__(128) ushort ldsB[2][128 * 32];
    // bijective XCD-chunked map: nwg = mtiles*8 (divisible by 8), per-XCD chunk = mtiles
    int j = blockIdx.x;
    int per = gridDim.x >> 3;            // = mtiles
    int wg = (j & 7) * per + (j >> 3);
    int bm = wg >> 3, bn = wg & 7;       // 8 bn of one bm consecutive on an XCD
    if (bm >= mtiles) return;

    int tid = threadIdx.x, lane = tid & 63, wid = tid >> 6;  // 8 waves
    int wm = wid >> 1, wn = wid & 1;     // 4x2 wave grid, each 64x64 output

    f32x4 acc[4][4];
#pragma unroll
    for (int m = 0; m < 4; m++)
#pragma unroll
        for (int nn = 0; nn < 4; nn++) acc[m][nn] = (f32x4){0.f, 0.f, 0.f, 0.f};

    // staging: BK=32 -> row = 64B = 4 segs of 16B. Wave w covers 16 rows (rr=lane>>2).
    // LDS linear [row][seg]; global source seg pre-XOR-swizzled by (lane>>4) (rule #21).
    int rr = lane >> 2;
    int sw = (lane & 3) ^ (lane >> 4);   // seg ^ (row>>2)&3, row = wid*16+rr
    const ushort* gA = A + (size_t)(bm * 256 + wid * 16 + rr) * DIM + sw * 8;
    const ushort* gB = Bt + (size_t)(bn * 128 + wid * 16 + rr) * DIM + sw * 8;
    int ldsbA0 = (wid * 16) * 32;        // chunk 0 rows [wid*16 .. +16)
    int ldsbA1 = (128 + wid * 16) * 32;  // chunk 1 rows [128+wid*16 .. +16)
    int ldsbB  = (wid * 16) * 32;

    int r16 = lane & 15, khi = lane >> 4, rs = (lane & 15) >> 2;

    auto stage = [&](int buf, int kt) {
        async_copy16(&ldsA[buf][ldsbA0], gA + kt * 32);
        async_copy16(&ldsA[buf][ldsbA1], gA + (size_t)128 * DIM + kt * 32);
        async_copy16(&ldsB[buf][ldsbB], gB + kt * 32);
    };

    stage(0, 0);
    int cur = 0;
    for (int kt = 0; kt < DIM / 32; ++kt) {
        if (kt + 1 < DIM / 32) {
            stage(cur ^ 1, kt + 1);                          // 3 more loads in flight
            asm volatile("s_waitcnt vmcnt(3)" ::: "memory"); // only stage kt's 3 must land
        } else {
            asm volatile("s_waitcnt vmcnt(0)" ::: "memory");
        }
        __builtin_amdgcn_s_barrier();          // raw: does NOT drain the prefetch
        __builtin_amdgcn_sched_barrier(0);
        {
            short8 af[4], bfv[4];
#pragma unroll
            for (int m = 0; m < 4; m++) {
                int row = wm * 64 + m * 16 + r16;
                af[m] = *(const short8*)&ldsA[cur][row * 32 + ((khi ^ rs) * 8)];
            }
#pragma unroll
            for (int nn = 0; nn < 4; nn++) {
                int row = wn * 64 + nn * 16 + r16;
                bfv[nn] = *(const short8*)&ldsB[cur][row * 32 + ((khi ^ rs) * 8)];
            }
#pragma unroll
            for (int m = 0; m < 4; m++)
#pragma unroll
                for (int nn = 0; nn < 4; nn++)
                    acc[m][nn] = __builtin_amdgcn_mfma_f32_16x16x32_bf16(af[m], bfv[nn], acc[m][nn], 0, 0, 0);
        }
        __builtin_amdgcn_sched_barrier(0);
        __builtin_amdgcn_s_barrier();          // all waves done reading buf before overwrite
        cur ^= 1;
    }

    // C/D mapping (m89): col = lane&15, row = (lane>>4)*4 + j
    int colbase = bn * 128 + wn * 64;
    int rowbase = bm * 256 + wm * 64 + khi * 4;
    if (EPI == 1) {
#pragma unroll
        for (int m = 0; m < 4; m++) {
#pragma unroll
            for (int jj = 0; jj < 4; jj++) {
                int r = rowbase + m * 16 + jj;
                if (r < mreal) {
                    float ns = nsrc[r];
#pragma unroll
                    for (int nn = 0; nn < 4; nn++) {
                        int col = colbase + nn * 16 + r16;
                        float v = acc[m][nn][jj] + bias[col] + feats[(size_t)r * DIM + col];
                        outp[(size_t)r * DIM + col] = f2bf(v * ns);
                    }
                }
            }
        }
    } else {
#pragma unroll
        for (int m = 0; m < 4; m++) {
#pragma unroll
            for (int jj = 0; jj < 4; jj++) {
                int r = rowbase + m * 16 + jj;
                if (r < mreal) {
#pragma unroll
                    for (int nn = 0; nn < 4; nn++) {
                        int col = colbase + nn * 16 + r16;
                        outp[(size_t)r * DIM + col] = f2bf(acc[m][nn][jj]);
                    }
                }
            }
        }
    }
}

// ---------------- fused aggregation + bias + relu + wnode column-reduction ----------------
// vec[c] += sum_v wnode[v] * relu( ndst[v] * sum_{e:dst=v} z[src_e][c] + b_g1[c] )

__global__ __launch_bounds__(256) void agg2_kernel(
    const ushort* __restrict__ z, const int* __restrict__ row_ptr,
    const int* __restrict__ in_deg, const int* __restrict__ csr_src,
    const float* __restrict__ ndst, const float* __restrict__ wnode,
    const float* __restrict__ bg1, float* __restrict__ vec, int n) {
    __shared__ float red[DIM];
    int lane = threadIdx.x & 63, wid = threadIdx.x >> 6;
    int wave = blockIdx.x * 4 + wid;
    int nwaves = gridDim.x * 4;
    int c0 = lane * 8;  // thread owns cols [c0,c0+8) and [512+c0, 512+c0+8)

    float bv[16];
#pragma unroll
    for (int t = 0; t < 8; t++) { bv[t] = bg1[c0 + t]; bv[8 + t] = bg1[512 + c0 + t]; }
    float part[16];
#pragma unroll
    for (int t = 0; t < 16; t++) part[t] = 0.f;

    for (int node = wave; node < n; node += nwaves) {
        int start = row_ptr[node], cnt = in_deg[node];
        float a[16];
#pragma unroll
        for (int t = 0; t < 16; t++) a[t] = 0.f;
        int e = 0;
        for (; e + 4 <= cnt; e += 4) {  // 4-edge unroll: 8 gather loads in flight
            const ushort* r0 = z + (size_t)csr_src[start + e] * DIM;
            const ushort* r1 = z + (size_t)csr_src[start + e + 1] * DIM;
            const ushort* r2 = z + (size_t)csr_src[start + e + 2] * DIM;
            const ushort* r3 = z + (size_t)csr_src[start + e + 3] * DIM;
            short8 v00 = *(const short8*)(r0 + c0);
            short8 v01 = *(const short8*)(r0 + 512 + c0);
            short8 v10 = *(const short8*)(r1 + c0);
            short8 v11 = *(const short8*)(r1 + 512 + c0);
            short8 v20 = *(const short8*)(r2 + c0);
            short8 v21 = *(const short8*)(r2 + 512 + c0);
            short8 v30 = *(const short8*)(r3 + c0);
            short8 v31 = *(const short8*)(r3 + 512 + c0);
#pragma unroll
            for (int t = 0; t < 8; t++) {
                a[t]     += (bf2f((ushort)v00[t]) + bf2f((ushort)v10[t])) +
                            (bf2f((ushort)v20[t]) + bf2f((ushort)v30[t]));
                a[8 + t] += (bf2f((ushort)v01[t]) + bf2f((ushort)v11[t])) +
                            (bf2f((ushort)v21[t]) + bf2f((ushort)v31[t]));
            }
        }
        for (; e < cnt; e++) {
            const ushort* r0 = z + (size_t)csr_src[start + e] * DIM;
            short8 v00 = *(const short8*)(r0 + c0);
            short8 v01 = *(const short8*)(r0 + 512 + c0);
#pragma unroll
            for (int t = 0; t < 8; t++) {
                a[t]     += bf2f((ushort)v00[t]);
                a[8 + t] += bf2f((ushort)v01[t]);
            }
        }
        float nd = ndst[node], w = wnode[node];
#pragma unroll
        for (int t = 0; t < 16; t++)
            part[t] = fmaf(w, fmaxf(fmaf(nd, a[t], bv[t]), 0.f), part[t]);
    }

    // block reduce across the 4 waves (same lane->col mapping) then one atomic pass
    if (wid == 0) {
#pragma unroll
        for (int t = 0; t < 8; t++) { red[c0 + t] = part[t]; red[512 + c0 + t] = part[8 + t]; }
    }
    __syncthreads();
    for (int w = 1; w < 4; ++w) {
        if (wid == w) {
#pragma unroll
            for (int t = 0; t < 8; t++) { red[c0 + t] += part[t]; red[512 + c0 + t] += part[8 + t]; }
        }
        __syncthreads();
    }
    for (int c = threadIdx.x; c < DIM; c += 256) atomicAdd(&vec[c], red[c]);
}

// ---------------- final GEMV: out = (1/N)*vec @ w_g2 + b_g2 ----------------

__global__ __launch_bounds__(256) void final_kernel(const float* __restrict__ vec,
                                                    const float* __restrict__ w2,
                                                    const float* __restrict__ b2,
                                                    float* out, float invn) {
    int d = blockIdx.x * 256 + threadIdx.x;
    int kb = blockIdx.y * 128;
    float acc = 0.f;
#pragma unroll 4
    for (int k = 0; k < 128; k++) acc = fmaf(vec[kb + k], w2[(size_t)(kb + k) * DIM + d], acc);
    float add = acc * invn + (blockIdx.y == 0 ? b2[d] : 0.f);
    atomicAdd(&out[d], add);
}

// ---------------- launch ----------------

extern "C" void kernel_launch(void* const* d_in, const int* in_sizes, int n_in,
                              void* d_out, int out_size, void* d_ws, size_t ws_size,
                              hipStream_t stream) {
    const float* feats  = (const float*)d_in[0];
    const float* boxes  = (const float*)d_in[1];
    const int*   esrc   = (const int*)d_in[2];
    const int*   edst   = (const int*)d_in[3];
    const float* w_pos1 = (const float*)d_in[4];
    const float* b_pos1 = (const float*)d_in[5];
    const float* w_pos2 = (const float*)d_in[6];
    const float* b_pos2 = (const float*)d_in[7];
    const float* w_g1   = (const float*)d_in[8];
    const float* b_g1   = (const float*)d_in[9];
    const float* w_g2   = (const float*)d_in[10];
    const float* b_g2   = (const float*)d_in[11];

    int n = in_sizes[0] / DIM;   // 20000
    int ee = in_sizes[2];        // 180000
    int mtiles = (n + 255) / 256;        // 79
    int gemm_grid = mtiles * 8;          // 632 blocks, 8 bn each

    char* p = (char*)d_ws;
    auto alloc = [&](size_t bytes) -> char* {
        char* r = p;
        p += (bytes + 255) & ~((size_t)255);
        return r;
    };
    size_t mp = (size_t)mtiles * 256;
    ushort* t_z    = (ushort*)alloc(mp * DIM * 2);  // t, later reused as z
    ushort* hs     = (ushort*)alloc(mp * DIM * 2);
    ushort* wt1    = (ushort*)alloc((size_t)DIM * DIM * 2);  // w_pos2^T bf16
    ushort* wt2    = (ushort*)alloc((size_t)DIM * DIM * 2);  // w_g1^T bf16
    char* zero_base = p;
    int*   out_deg = (int*)alloc((size_t)n * 4);
    int*   in_deg  = (int*)alloc((size_t)n * 4);
    float* cw      = (float*)alloc((size_t)n * 4);   // c, then w_node in place
    float* vec     = (float*)alloc((size_t)DIM * 4);
    size_t zero_bytes = (size_t)(p - zero_base);
    float* nsrc    = (float*)alloc((size_t)n * 4);
    float* ndst    = (float*)alloc((size_t)n * 4);
    int*   row_ptr = (int*)alloc((size_t)(n + 1) * 4);
    int*   cursor  = (int*)alloc((size_t)n * 4);
    int*   csr_src = (int*)alloc((size_t)ee * 4);

    hipMemsetAsync(zero_base, 0, zero_bytes, stream);
    hipMemsetAsync(d_out, 0, (size_t)out_size * 4, stream);

    int eb = (ee + 255) / 256;
    int nb = (n + 255) / 256;

    deg_kernel<<<eb, 256, 0, stream>>>(esrc, edst, out_deg, in_deg, ee);
    posA_kernel<<<256, 256, 0, stream>>>(boxes, w_pos1, b_pos1, t_z, n);
    transpose_bf16_kernel<<<dim3(32, 32), 256, 0, stream>>>(w_pos2, wt1);
    transpose_bf16_kernel<<<dim3(32, 32), 256, 0, stream>>>(w_g1, wt2);
    norm_kernel<<<nb, 256, 0, stream>>>(out_deg, in_deg, nsrc, ndst, n);
    csum_kernel<<<eb, 256, 0, stream>>>(esrc, edst, ndst, cw, ee);
    scan_kernel<<<1, 1024, 0, stream>>>(in_deg, row_ptr, cursor, n);
    wnode_kernel<<<nb, 256, 0, stream>>>(cw, nsrc, n);
    scatter_kernel<<<eb, 256, 0, stream>>>(esrc, edst, cursor, csr_src, ee);

    // GEMM1: hs = bf16((t @ w_pos2 + b_pos2 + feats) * norm_src)
    gemm_kernel<1><<<gemm_grid, 512, 0, stream>>>(t_z, wt1, b_pos2, feats, nsrc, hs, mtiles, n);
    // GEMM2: z = bf16(hs @ w_g1)   (t buffer dead -> reuse as z)
    gemm_kernel<0><<<gemm_grid, 512, 0, stream>>>(hs, wt2, nullptr, nullptr, nullptr, t_z, mtiles, n);
    // fused aggregation + bias + relu + wnode reduction
    agg2_kernel<<<2048, 256, 0, stream>>>(t_z, row_ptr, in_deg, csr_src, ndst, cw, b_g1, vec, n);
    final_kernel<<<dim3(4, 8), 256, 0, stream>>>(vec, w_g2, b_g2, (float*)d_out, 1.0f / (float)n);
}

// Round 7
// 481.200 us; speedup vs baseline: 1.5790x; 1.5790x over previous
//
#include <hip/hip_runtime.h>
#include <hip/hip_bf16.h>
#include <stdint.h>

#define DIM 1024

typedef __attribute__((ext_vector_type(4))) float f32x4;
typedef __attribute__((ext_vector_type(8))) short short8;

__device__ __forceinline__ float bf2f(ushort u) {
    union { uint32_t u; float f; } c; c.u = ((uint32_t)u) << 16; return c.f;
}
__device__ __forceinline__ ushort f2bf(float f) {
    union { float f; uint32_t u; } c; c.f = f;
    uint32_t r = (c.u + 0x7fffu + ((c.u >> 16) & 1u)) >> 16;
    return (ushort)r;
}

// async global->LDS, 16B per lane. LDS dest is wave-uniform base (+lane*16 implicit).
__device__ __forceinline__ void async_copy16(void* lds, const void* g) {
    __builtin_amdgcn_global_load_lds((const __attribute__((address_space(1))) void*)g,
                                     (__attribute__((address_space(3))) void*)lds, 16, 0, 0);
}

// ---------------- small graph-prep kernels ----------------

__global__ void deg_kernel(const int* __restrict__ src, const int* __restrict__ dst,
                           int* out_deg, int* in_deg, int ee) {
    int e = blockIdx.x * 256 + threadIdx.x;
    if (e < ee) {
        atomicAdd(&out_deg[src[e]], 1);
        atomicAdd(&in_deg[dst[e]], 1);
    }
}

__global__ void norm_kernel(const int* __restrict__ out_deg, const int* __restrict__ in_deg,
                            float* ns, float* nd, int n) {
    int i = blockIdx.x * 256 + threadIdx.x;
    if (i < n) {
        int od = out_deg[i], id = in_deg[i];
        ns[i] = od > 0 ? rsqrtf((float)od) : 0.f;
        nd[i] = id > 0 ? rsqrtf((float)id) : 0.f;
    }
}

__global__ void csum_kernel(const int* __restrict__ src, const int* __restrict__ dst,
                            const float* __restrict__ nd, float* cw, int ee) {
    int e = blockIdx.x * 256 + threadIdx.x;
    if (e < ee) atomicAdd(&cw[src[e]], nd[dst[e]]);
}

// single-block shuffle-based exclusive scan of in_deg -> row_ptr + cursor (1024 threads)
__global__ void scan_kernel(const int* __restrict__ deg, int* row_ptr, int* cursor, int n) {
    __shared__ int wsum[16];
    __shared__ int carry_s;
    int tid = threadIdx.x, lane = tid & 63, wid = tid >> 6;
    if (tid == 0) carry_s = 0;
    __syncthreads();
    for (int base = 0; base < n; base += 1024) {
        int x = (base + tid < n) ? deg[base + tid] : 0;
        int v = x;
#pragma unroll
        for (int off = 1; off < 64; off <<= 1) {
            int u = __shfl_up(v, off);
            if (lane >= off) v += u;
        }
        if (lane == 63) wsum[wid] = v;
        __syncthreads();
        if (wid == 0 && lane < 16) {
            int wv = wsum[lane];
#pragma unroll
            for (int off = 1; off < 16; off <<= 1) {
                int wu = __shfl_up(wv, off);
                if (lane >= off) wv += wu;
            }
            wsum[lane] = wv;
        }
        __syncthreads();
        int waveoff = (wid > 0) ? wsum[wid - 1] : 0;
        if (base + tid < n) {
            int ex = carry_s + waveoff + v - x;
            row_ptr[base + tid] = ex;
            cursor[base + tid] = ex;
        }
        __syncthreads();
        if (tid == 0) carry_s += wsum[15];
        __syncthreads();
    }
}

__global__ void wnode_kernel(float* cw, const float* __restrict__ ns, int n) {
    int i = blockIdx.x * 256 + threadIdx.x;
    if (i < n) cw[i] *= ns[i];  // w_node = norm_src * c
}

__global__ void scatter_kernel(const int* __restrict__ src, const int* __restrict__ dst,
                               int* cursor, int* csr_src, int ee) {
    int e = blockIdx.x * 256 + threadIdx.x;
    if (e < ee) {
        int p = atomicAdd(&cursor[dst[e]], 1);
        csr_src[p] = src[e];
    }
}

// ---------------- pos MLP stage A: t = relu(clip(boxes) @ w_pos1 + b_pos1), bf16 ----------------

__global__ __launch_bounds__(256) void posA_kernel(const float* __restrict__ boxes,
                                                   const float* __restrict__ w1,
                                                   const float* __restrict__ b1,
                                                   ushort* __restrict__ t, int n) {
    int lane = threadIdx.x & 63, wid = threadIdx.x >> 6;
    int wave = blockIdx.x * 4 + wid, nw = gridDim.x * 4;
    int c0 = lane * 16;
    for (int row = wave; row < n; row += nw) {
        float b[4];
#pragma unroll
        for (int j = 0; j < 4; j++) {
            float v = boxes[row * 4 + j];
            b[j] = fminf(fmaxf(v, -10.f), 10.f);
        }
        short8 o[2];
#pragma unroll
        for (int h = 0; h < 2; h++) {
#pragma unroll
            for (int q = 0; q < 8; q++) {
                int col = c0 + h * 8 + q;
                float v = b1[col];
#pragma unroll
                for (int j = 0; j < 4; j++) v = fmaf(b[j], w1[j * DIM + col], v);
                o[h][q] = (short)f2bf(fmaxf(v, 0.f));
            }
        }
        *(short8*)(t + (size_t)row * DIM + c0) = o[0];
        *(short8*)(t + (size_t)row * DIM + c0 + 8) = o[1];
    }
}

// ---------------- weight transpose+convert: wt[n][k] = bf16(w[k][n]) ----------------

__global__ __launch_bounds__(256) void transpose_bf16_kernel(const float* __restrict__ w,
                                                             ushort* __restrict__ wt) {
    __shared__ float tile[32][33];
    int bx = blockIdx.x, by = blockIdx.y;
    int tx = threadIdx.x & 31, ty = threadIdx.x >> 5;  // 32x8
#pragma unroll
    for (int r = 0; r < 32; r += 8)
        tile[ty + r][tx] = w[(size_t)(by * 32 + ty + r) * DIM + bx * 32 + tx];
    __syncthreads();
#pragma unroll
    for (int r = 0; r < 32; r += 8)
        wt[(size_t)(bx * 32 + ty + r) * DIM + by * 32 + tx] = f2bf(tile[tx][ty + r]);
}

// ---------------- 256x128 bf16 MFMA GEMM, BK=64, depth-3 pipelined, counted vmcnt ----------
// 8 waves (4Mx2N), per-wave 64x64 (acc[4][4], 0.5 ds_read/MFMA). 3 LDS buffers = 144 KB,
// 1 block/CU. Per K-tile: vmcnt(12) [2 stages in flight] -> barrier -> 2x{8 ds_read +
// setprio + 16 MFMA} -> barrier -> stage kt+3. Loads get 2 K-tile computes of cover.
// Grid 632 = 8 XCD x 79, bijective chunked map.
// EPI==0: outp = bf16(C);  EPI==1: outp = bf16((C + bias + feats) * nsrc[row])

template <int EPI>
__global__ __launch_bounds__(512, 2) void gemm_kernel(
    const ushort* __restrict__ A, const ushort* __restrict__ Bt,
    const float* __restrict__ bias, const float* __restrict__ feats,
    const float* __restrict__ nsrc, ushort* __restrict__ outp,
    int mtiles, int mreal) {
    __shared__ __align__(128) ushort ldsA[3][256 * 64];
    __shared__ __align__(128) ushort ldsB[3][128 * 64];
    int j = blockIdx.x;
    int per = gridDim.x >> 3;            // = mtiles
    int wg = (j & 7) * per + (j >> 3);   // 8 bn of one bm consecutive on one XCD
    int bm = wg >> 3, bn = wg & 7;
    if (bm >= mtiles) return;

    int tid = threadIdx.x, lane = tid & 63, wid = tid >> 6;  // 8 waves
    int wm = wid >> 1, wn = wid & 1;     // 4Mx2N, each wave 64x64 output

    f32x4 acc[4][4];
#pragma unroll
    for (int m = 0; m < 4; m++)
#pragma unroll
        for (int nn = 0; nn < 4; nn++) acc[m][nn] = (f32x4){0.f, 0.f, 0.f, 0.f};

    // staging: BK=64 -> 8 segs of 16B per row. Wave w covers rows {w*8 + c*64}.
    // LDS linear [row][seg]; global source seg pre-XOR-swizzled by row&7 (rule #21).
    int srow = wid * 8 + (lane >> 3);            // row within 64-row chunk
    int sseg = (lane & 7) ^ (lane >> 3);         // seg ^ (row&7)
    const ushort* gA = A + (size_t)(bm * 256 + srow) * DIM + sseg * 8;
    const ushort* gB = Bt + (size_t)(bn * 128 + srow) * DIM + sseg * 8;
    int lbase = (wid * 8) * 64;

    int r16 = lane & 15, khi = lane >> 4, rx = lane & 7;

    auto stage = [&](int buf, int kt) {      // 6 global_load_lds per wave
#pragma unroll
        for (int c = 0; c < 4; c++)
            async_copy16(&ldsA[buf][lbase + c * 64 * 64], gA + (size_t)c * 64 * DIM + kt * 64);
#pragma unroll
        for (int c = 0; c < 2; c++)
            async_copy16(&ldsB[buf][lbase + c * 64 * 64], gB + (size_t)c * 64 * DIM + kt * 64);
    };

    stage(0, 0);
    stage(1, 1);
    stage(2, 2);                             // 18 loads in flight
    for (int kt = 0; kt < DIM / 64; ++kt) {
        if (kt <= DIM / 64 - 3) {
            asm volatile("s_waitcnt vmcnt(12)" ::: "memory");   // kt's 6 landed
        } else if (kt == DIM / 64 - 2) {
            asm volatile("s_waitcnt vmcnt(6)" ::: "memory");
        } else {
            asm volatile("s_waitcnt vmcnt(0)" ::: "memory");
        }
        __builtin_amdgcn_s_barrier();
        __builtin_amdgcn_sched_barrier(0);
        int cur = kt % 3;
#pragma unroll
        for (int kk = 0; kk < 2; kk++) {
            short8 af[4], bfv[4];
#pragma unroll
            for (int m = 0; m < 4; m++) {
                int row = wm * 64 + m * 16 + r16;
                int seg = (kk * 4 + khi) ^ (row & 7);
                af[m] = *(const short8*)&ldsA[cur][row * 64 + seg * 8];
            }
#pragma unroll
            for (int nn = 0; nn < 4; nn++) {
                int row = wn * 64 + nn * 16 + r16;
                int seg = (kk * 4 + khi) ^ (row & 7);
                bfv[nn] = *(const short8*)&ldsB[cur][row * 64 + seg * 8];
            }
            __builtin_amdgcn_s_setprio(1);
#pragma unroll
            for (int m = 0; m < 4; m++)
#pragma unroll
                for (int nn = 0; nn < 4; nn++)
                    acc[m][nn] = __builtin_amdgcn_mfma_f32_16x16x32_bf16(af[m], bfv[nn], acc[m][nn], 0, 0, 0);
            __builtin_amdgcn_s_setprio(0);
        }
        __builtin_amdgcn_sched_barrier(0);
        __builtin_amdgcn_s_barrier();        // all waves done reading buf[cur]
        __builtin_amdgcn_sched_barrier(0);
        if (kt + 3 < DIM / 64) stage(cur, kt + 3);  // overwrite freed buffer
    }

    // C/D mapping (m89): col = lane&15, row = (lane>>4)*4 + j
    int colbase = bn * 128 + wn * 64;
    int rowbase = bm * 256 + wm * 64 + khi * 4;
    if (EPI == 1) {
#pragma unroll
        for (int m = 0; m < 4; m++) {
#pragma unroll
            for (int jj = 0; jj < 4; jj++) {
                int r = rowbase + m * 16 + jj;
                if (r < mreal) {
                    float ns = nsrc[r];
#pragma unroll
                    for (int nn = 0; nn < 4; nn++) {
                        int col = colbase + nn * 16 + r16;
                        float v = acc[m][nn][jj] + bias[col] + feats[(size_t)r * DIM + col];
                        outp[(size_t)r * DIM + col] = f2bf(v * ns);
                    }
                }
            }
        }
    } else {
#pragma unroll
        for (int m = 0; m < 4; m++) {
#pragma unroll
            for (int jj = 0; jj < 4; jj++) {
                int r = rowbase + m * 16 + jj;
                if (r < mreal) {
#pragma unroll
                    for (int nn = 0; nn < 4; nn++) {
                        int col = colbase + nn * 16 + r16;
                        outp[(size_t)r * DIM + col] = f2bf(acc[m][nn][jj]);
                    }
                }
            }
        }
    }
}

// ---------------- fused aggregation + bias + relu + wnode column-reduction ----------------
// vec[c] += sum_v wnode[v] * relu( ndst[v] * sum_{e:dst=v} z[src_e][c] + b_g1[c] )

__global__ __launch_bounds__(256) void agg2_kernel(
    const ushort* __restrict__ z, const int* __restrict__ row_ptr,
    const int* __restrict__ in_deg, const int* __restrict__ csr_src,
    const float* __restrict__ ndst, const float* __restrict__ wnode,
    const float* __restrict__ bg1, float* __restrict__ vec, int n) {
    __shared__ float red[DIM];
    int lane = threadIdx.x & 63, wid = threadIdx.x >> 6;
    int wave = blockIdx.x * 4 + wid;
    int nwaves = gridDim.x * 4;
    int c0 = lane * 8;  // thread owns cols [c0,c0+8) and [512+c0, 512+c0+8)

    float bv[16];
#pragma unroll
    for (int t = 0; t < 8; t++) { bv[t] = bg1[c0 + t]; bv[8 + t] = bg1[512 + c0 + t]; }
    float part[16];
#pragma unroll
    for (int t = 0; t < 16; t++) part[t] = 0.f;

    for (int node = wave; node < n; node += nwaves) {
        int start = row_ptr[node], cnt = in_deg[node];
        float a[16];
#pragma unroll
        for (int t = 0; t < 16; t++) a[t] = 0.f;
        int e = 0;
        for (; e + 4 <= cnt; e += 4) {  // 4-edge unroll: 8 gather loads in flight
            const ushort* r0 = z + (size_t)csr_src[start + e] * DIM;
            const ushort* r1 = z + (size_t)csr_src[start + e + 1] * DIM;
            const ushort* r2 = z + (size_t)csr_src[start + e + 2] * DIM;
            const ushort* r3 = z + (size_t)csr_src[start + e + 3] * DIM;
            short8 v00 = *(const short8*)(r0 + c0);
            short8 v01 = *(const short8*)(r0 + 512 + c0);
            short8 v10 = *(const short8*)(r1 + c0);
            short8 v11 = *(const short8*)(r1 + 512 + c0);
            short8 v20 = *(const short8*)(r2 + c0);
            short8 v21 = *(const short8*)(r2 + 512 + c0);
            short8 v30 = *(const short8*)(r3 + c0);
            short8 v31 = *(const short8*)(r3 + 512 + c0);
#pragma unroll
            for (int t = 0; t < 8; t++) {
                a[t]     += (bf2f((ushort)v00[t]) + bf2f((ushort)v10[t])) +
                            (bf2f((ushort)v20[t]) + bf2f((ushort)v30[t]));
                a[8 + t] += (bf2f((ushort)v01[t]) + bf2f((ushort)v11[t])) +
                            (bf2f((ushort)v21[t]) + bf2f((ushort)v31[t]));
            }
        }
        for (; e < cnt; e++) {
            const ushort* r0 = z + (size_t)csr_src[start + e] * DIM;
            short8 v00 = *(const short8*)(r0 + c0);
            short8 v01 = *(const short8*)(r0 + 512 + c0);
#pragma unroll
            for (int t = 0; t < 8; t++) {
                a[t]     += bf2f((ushort)v00[t]);
                a[8 + t] += bf2f((ushort)v01[t]);
            }
        }
        float nd = ndst[node], w = wnode[node];
#pragma unroll
        for (int t = 0; t < 16; t++)
            part[t] = fmaf(w, fmaxf(fmaf(nd, a[t], bv[t]), 0.f), part[t]);
    }

    // block reduce across the 4 waves (same lane->col mapping) then one atomic pass
    if (wid == 0) {
#pragma unroll
        for (int t = 0; t < 8; t++) { red[c0 + t] = part[t]; red[512 + c0 + t] = part[8 + t]; }
    }
    __syncthreads();
    for (int w = 1; w < 4; ++w) {
        if (wid == w) {
#pragma unroll
            for (int t = 0; t < 8; t++) { red[c0 + t] += part[t]; red[512 + c0 + t] += part[8 + t]; }
        }
        __syncthreads();
    }
    for (int c = threadIdx.x; c < DIM; c += 256) atomicAdd(&vec[c], red[c]);
}

// ---------------- final GEMV: out = (1/N)*vec @ w_g2 + b_g2 ----------------

__global__ __launch_bounds__(256) void final_kernel(const float* __restrict__ vec,
                                                    const float* __restrict__ w2,
                                                    const float* __restrict__ b2,
                                                    float* out, float invn) {
    int d = blockIdx.x * 256 + threadIdx.x;
    int kb = blockIdx.y * 128;
    float acc = 0.f;
#pragma unroll 4
    for (int k = 0; k < 128; k++) acc = fmaf(vec[kb + k], w2[(size_t)(kb + k) * DIM + d], acc);
    float add = acc * invn + (blockIdx.y == 0 ? b2[d] : 0.f);
    atomicAdd(&out[d], add);
}

// ---------------- launch ----------------

extern "C" void kernel_launch(void* const* d_in, const int* in_sizes, int n_in,
                              void* d_out, int out_size, void* d_ws, size_t ws_size,
                              hipStream_t stream) {
    const float* feats  = (const float*)d_in[0];
    const float* boxes  = (const float*)d_in[1];
    const int*   esrc   = (const int*)d_in[2];
    const int*   edst   = (const int*)d_in[3];
    const float* w_pos1 = (const float*)d_in[4];
    const float* b_pos1 = (const float*)d_in[5];
    const float* w_pos2 = (const float*)d_in[6];
    const float* b_pos2 = (const float*)d_in[7];
    const float* w_g1   = (const float*)d_in[8];
    const float* b_g1   = (const float*)d_in[9];
    const float* w_g2   = (const float*)d_in[10];
    const float* b_g2   = (const float*)d_in[11];

    int n = in_sizes[0] / DIM;   // 20000
    int ee = in_sizes[2];        // 180000
    int mtiles = (n + 255) / 256;        // 79
    int gemm_grid = mtiles * 8;          // 632 blocks, 8 bn each

    char* p = (char*)d_ws;
    auto alloc = [&](size_t bytes) -> char* {
        char* r = p;
        p += (bytes + 255) & ~((size_t)255);
        return r;
    };
    size_t mp = (size_t)mtiles * 256;
    ushort* t_z    = (ushort*)alloc(mp * DIM * 2);  // t, later reused as z
    ushort* hs     = (ushort*)alloc(mp * DIM * 2);
    ushort* wt1    = (ushort*)alloc((size_t)DIM * DIM * 2);  // w_pos2^T bf16
    ushort* wt2    = (ushort*)alloc((size_t)DIM * DIM * 2);  // w_g1^T bf16
    char* zero_base = p;
    int*   out_deg = (int*)alloc((size_t)n * 4);
    int*   in_deg  = (int*)alloc((size_t)n * 4);
    float* cw      = (float*)alloc((size_t)n * 4);   // c, then w_node in place
    float* vec     = (float*)alloc((size_t)DIM * 4);
    size_t zero_bytes = (size_t)(p - zero_base);
    float* nsrc    = (float*)alloc((size_t)n * 4);
    float* ndst    = (float*)alloc((size_t)n * 4);
    int*   row_ptr = (int*)alloc((size_t)(n + 1) * 4);
    int*   cursor  = (int*)alloc((size_t)n * 4);
    int*   csr_src = (int*)alloc((size_t)ee * 4);

    hipMemsetAsync(zero_base, 0, zero_bytes, stream);
    hipMemsetAsync(d_out, 0, (size_t)out_size * 4, stream);

    int eb = (ee + 255) / 256;
    int nb = (n + 255) / 256;

    deg_kernel<<<eb, 256, 0, stream>>>(esrc, edst, out_deg, in_deg, ee);
    posA_kernel<<<256, 256, 0, stream>>>(boxes, w_pos1, b_pos1, t_z, n);
    transpose_bf16_kernel<<<dim3(32, 32), 256, 0, stream>>>(w_pos2, wt1);
    transpose_bf16_kernel<<<dim3(32, 32), 256, 0, stream>>>(w_g1, wt2);
    norm_kernel<<<nb, 256, 0, stream>>>(out_deg, in_deg, nsrc, ndst, n);
    csum_kernel<<<eb, 256, 0, stream>>>(esrc, edst, ndst, cw, ee);
    scan_kernel<<<1, 1024, 0, stream>>>(in_deg, row_ptr, cursor, n);
    wnode_kernel<<<nb, 256, 0, stream>>>(cw, nsrc, n);
    scatter_kernel<<<eb, 256, 0, stream>>>(esrc, edst, cursor, csr_src, ee);

    // GEMM1: hs = bf16((t @ w_pos2 + b_pos2 + feats) * norm_src)
    gemm_kernel<1><<<gemm_grid, 512, 0, stream>>>(t_z, wt1, b_pos2, feats, nsrc, hs, mtiles, n);
    // GEMM2: z = bf16(hs @ w_g1)   (t buffer dead -> reuse as z)
    gemm_kernel<0><<<gemm_grid, 512, 0, stream>>>(hs, wt2, nullptr, nullptr, nullptr, t_z, mtiles, n);
    // fused aggregation + bias + relu + wnode reduction
    agg2_kernel<<<2048, 256, 0, stream>>>(t_z, row_ptr, in_deg, csr_src, ndst, cw, b_g1, vec, n);
    final_kernel<<<dim3(4, 8), 256, 0, stream>>>(vec, w_g2, b_g2, (float*)d_out, 1.0f / (float)n);
}

// Round 8
// 424.214 us; speedup vs baseline: 1.7911x; 1.1343x over previous
//
#include <hip/hip_runtime.h>
#include <hip/hip_bf16.h>
#include <stdint.h>

#define DIM 1024

typedef __attribute__((ext_vector_type(4))) float f32x4;
typedef __attribute__((ext_vector_type(2))) float f32x2;
typedef __attribute__((ext_vector_type(8))) short short8;

__device__ __forceinline__ float bf2f(ushort u) {
    union { uint32_t u; float f; } c; c.u = ((uint32_t)u) << 16; return c.f;
}
__device__ __forceinline__ ushort f2bf(float f) {
    union { float f; uint32_t u; } c; c.f = f;
    uint32_t r = (c.u + 0x7fffu + ((c.u >> 16) & 1u)) >> 16;
    return (ushort)r;
}
// f32 -> fp8 e4m3 (OCP) via HW cvt; returns low byte.
__device__ __forceinline__ uint8_t f2fp8(float v) {
    int b;
    asm("v_cvt_pk_fp8_f32 %0, %1, %2" : "=v"(b) : "v"(v), "v"(v));
    return (uint8_t)b;
}
// 4 fp8 (one dword) -> accumulate into a[0..3]
__device__ __forceinline__ void acc_fp8x4(uint32_t dw, float* a) {
    f32x2 lo, hi;
    asm("v_cvt_pk_f32_fp8 %0, %1" : "=v"(lo) : "v"(dw));
    uint32_t dwh = dw >> 16;
    asm("v_cvt_pk_f32_fp8 %0, %1" : "=v"(hi) : "v"(dwh));
    a[0] += lo[0]; a[1] += lo[1]; a[2] += hi[0]; a[3] += hi[1];
}

// async global->LDS, 16B per lane. LDS dest is wave-uniform base (+lane*16 implicit).
__device__ __forceinline__ void async_copy16(void* lds, const void* g) {
    __builtin_amdgcn_global_load_lds((const __attribute__((address_space(1))) void*)g,
                                     (__attribute__((address_space(3))) void*)lds, 16, 0, 0);
}

// ---------------- small graph-prep kernels ----------------

__global__ void deg_kernel(const int* __restrict__ src, const int* __restrict__ dst,
                           int* out_deg, int* in_deg, int ee) {
    int e = blockIdx.x * 256 + threadIdx.x;
    if (e < ee) {
        atomicAdd(&out_deg[src[e]], 1);
        atomicAdd(&in_deg[dst[e]], 1);
    }
}

__global__ void norm_kernel(const int* __restrict__ out_deg, const int* __restrict__ in_deg,
                            float* ns, float* nd, int n) {
    int i = blockIdx.x * 256 + threadIdx.x;
    if (i < n) {
        int od = out_deg[i], id = in_deg[i];
        ns[i] = od > 0 ? rsqrtf((float)od) : 0.f;
        nd[i] = id > 0 ? rsqrtf((float)id) : 0.f;
    }
}

__global__ void csum_kernel(const int* __restrict__ src, const int* __restrict__ dst,
                            const float* __restrict__ nd, float* cw, int ee) {
    int e = blockIdx.x * 256 + threadIdx.x;
    if (e < ee) atomicAdd(&cw[src[e]], nd[dst[e]]);
}

// single-block shuffle-based exclusive scan of in_deg -> row_ptr + cursor (1024 threads)
__global__ void scan_kernel(const int* __restrict__ deg, int* row_ptr, int* cursor, int n) {
    __shared__ int wsum[16];
    __shared__ int carry_s;
    int tid = threadIdx.x, lane = tid & 63, wid = tid >> 6;
    if (tid == 0) carry_s = 0;
    __syncthreads();
    for (int base = 0; base < n; base += 1024) {
        int x = (base + tid < n) ? deg[base + tid] : 0;
        int v = x;
#pragma unroll
        for (int off = 1; off < 64; off <<= 1) {
            int u = __shfl_up(v, off);
            if (lane >= off) v += u;
        }
        if (lane == 63) wsum[wid] = v;
        __syncthreads();
        if (wid == 0 && lane < 16) {
            int wv = wsum[lane];
#pragma unroll
            for (int off = 1; off < 16; off <<= 1) {
                int wu = __shfl_up(wv, off);
                if (lane >= off) wv += wu;
            }
            wsum[lane] = wv;
        }
        __syncthreads();
        int waveoff = (wid > 0) ? wsum[wid - 1] : 0;
        if (base + tid < n) {
            int ex = carry_s + waveoff + v - x;
            row_ptr[base + tid] = ex;
            cursor[base + tid] = ex;
        }
        __syncthreads();
        if (tid == 0) carry_s += wsum[15];
        __syncthreads();
    }
}

__global__ void wnode_kernel(float* cw, const float* __restrict__ ns, int n) {
    int i = blockIdx.x * 256 + threadIdx.x;
    if (i < n) cw[i] *= ns[i];  // w_node = norm_src * c
}

__global__ void scatter_kernel(const int* __restrict__ src, const int* __restrict__ dst,
                               int* cursor, int* csr_src, int ee) {
    int e = blockIdx.x * 256 + threadIdx.x;
    if (e < ee) {
        int p = atomicAdd(&cursor[dst[e]], 1);
        csr_src[p] = src[e];
    }
}

// ---------------- pos MLP stage A: t = relu(clip(boxes) @ w_pos1 + b_pos1), bf16 ----------------

__global__ __launch_bounds__(256) void posA_kernel(const float* __restrict__ boxes,
                                                   const float* __restrict__ w1,
                                                   const float* __restrict__ b1,
                                                   ushort* __restrict__ t, int n) {
    int lane = threadIdx.x & 63, wid = threadIdx.x >> 6;
    int wave = blockIdx.x * 4 + wid, nw = gridDim.x * 4;
    int c0 = lane * 16;
    for (int row = wave; row < n; row += nw) {
        float b[4];
#pragma unroll
        for (int j = 0; j < 4; j++) {
            float v = boxes[row * 4 + j];
            b[j] = fminf(fmaxf(v, -10.f), 10.f);
        }
        short8 o[2];
#pragma unroll
        for (int h = 0; h < 2; h++) {
#pragma unroll
            for (int q = 0; q < 8; q++) {
                int col = c0 + h * 8 + q;
                float v = b1[col];
#pragma unroll
                for (int j = 0; j < 4; j++) v = fmaf(b[j], w1[j * DIM + col], v);
                o[h][q] = (short)f2bf(fmaxf(v, 0.f));
            }
        }
        *(short8*)(t + (size_t)row * DIM + c0) = o[0];
        *(short8*)(t + (size_t)row * DIM + c0 + 8) = o[1];
    }
}

// ---------------- weight transpose+convert: wt[n][k] = bf16(w[k][n]) ----------------

__global__ __launch_bounds__(256) void transpose_bf16_kernel(const float* __restrict__ w,
                                                             ushort* __restrict__ wt) {
    __shared__ float tile[32][33];
    int bx = blockIdx.x, by = blockIdx.y;
    int tx = threadIdx.x & 31, ty = threadIdx.x >> 5;  // 32x8
#pragma unroll
    for (int r = 0; r < 32; r += 8)
        tile[ty + r][tx] = w[(size_t)(by * 32 + ty + r) * DIM + bx * 32 + tx];
    __syncthreads();
#pragma unroll
    for (int r = 0; r < 32; r += 8)
        wt[(size_t)(bx * 32 + ty + r) * DIM + by * 32 + tx] = f2bf(tile[tx][ty + r]);
}

// ---------------- 128x128 bf16 MFMA GEMM, BK=64, 8 waves, counted-vmcnt dbuf (R5 struct) ----
// Grid: flat, XCD-grouped: j&7 = XCD, all 8 bn for a bm run consecutively on one XCD.
// EPI==0: outp = fp8_e4m3(C * 16)                         (rows < mreal)  [z path]
// EPI==1: outp = bf16((C + bias + feats) * nsrc[row])     (rows < mreal)  [hs path]

template <int EPI>
__global__ __launch_bounds__(512, 4) void gemm_kernel(
    const ushort* __restrict__ A, const ushort* __restrict__ Bt,
    const float* __restrict__ bias, const float* __restrict__ feats,
    const float* __restrict__ nsrc, void* __restrict__ outp,
    int mtiles, int mreal) {
    __shared__ __align__(128) ushort ldsA[2][128 * 64];
    __shared__ __align__(128) ushort ldsB[2][128 * 64];
    int j = blockIdx.x;
    int xcd = j & 7, kq = j >> 3;
    int bm = xcd + 8 * (kq >> 3);
    int bn = kq & 7;
    if (bm >= mtiles) return;

    int tid = threadIdx.x, lane = tid & 63, wid = tid >> 6;  // 8 waves
    int wm = wid >> 1, wn = wid & 1;  // 4x2 wave grid, each 32x64 output

    f32x4 acc[2][4];
#pragma unroll
    for (int m = 0; m < 2; m++)
#pragma unroll
        for (int nn = 0; nn < 4; nn++) acc[m][nn] = (f32x4){0.f, 0.f, 0.f, 0.f};

    // staging: wave w covers rows {w*8 + c*64} (8 rows per load), A and B -> 4 loads/wave/stage.
    // LDS linear [row][seg]; global source seg pre-XOR-swizzled (rule #21).
    int srow = wid * 8 + (lane >> 3);
    int sseg = (lane & 7) ^ (lane >> 3);
    const ushort* gA = A + (size_t)(bm * 128 + srow) * DIM + sseg * 8;
    const ushort* gB = Bt + (size_t)(bn * 128 + srow) * DIM + sseg * 8;
    int ldsoff0 = (wid * 8) * 64;

    int r16 = lane & 15, khi = lane >> 4;

    auto stage = [&](int buf, int kt) {
#pragma unroll
        for (int c = 0; c < 2; c++) {
            async_copy16(&ldsA[buf][ldsoff0 + c * 64 * 64], gA + (size_t)c * 64 * DIM + kt * 64);
            async_copy16(&ldsB[buf][ldsoff0 + c * 64 * 64], gB + (size_t)c * 64 * DIM + kt * 64);
        }
    };

    stage(0, 0);
    int cur = 0;
    for (int kt = 0; kt < DIM / 64; ++kt) {
        if (kt + 1 < DIM / 64) {
            stage(cur ^ 1, kt + 1);                         // 4 more loads in flight
            asm volatile("s_waitcnt vmcnt(4)" ::: "memory");  // only stage kt's 4 must land
        } else {
            asm volatile("s_waitcnt vmcnt(0)" ::: "memory");
        }
        __builtin_amdgcn_s_barrier();          // raw: does NOT drain the prefetch
        __builtin_amdgcn_sched_barrier(0);
#pragma unroll
        for (int kk = 0; kk < 2; kk++) {
            short8 af[2], bfv[4];
#pragma unroll
            for (int m = 0; m < 2; m++) {
                int row = wm * 32 + m * 16 + r16;
                int seg = (kk * 4 + khi) ^ (row & 7);
                af[m] = *(const short8*)&ldsA[cur][row * 64 + seg * 8];
            }
#pragma unroll
            for (int nn = 0; nn < 4; nn++) {
                int row = wn * 64 + nn * 16 + r16;
                int seg = (kk * 4 + khi) ^ (row & 7);
                bfv[nn] = *(const short8*)&ldsB[cur][row * 64 + seg * 8];
            }
#pragma unroll
            for (int m = 0; m < 2; m++)
#pragma unroll
                for (int nn = 0; nn < 4; nn++)
                    acc[m][nn] = __builtin_amdgcn_mfma_f32_16x16x32_bf16(af[m], bfv[nn], acc[m][nn], 0, 0, 0);
        }
        __builtin_amdgcn_sched_barrier(0);
        __builtin_amdgcn_s_barrier();          // all waves done reading buf before overwrite
        cur ^= 1;
    }

    // C/D mapping (m89): col = lane&15, row = (lane>>4)*4 + j
    int colbase = bn * 128 + wn * 64;
    int rowbase = bm * 128 + wm * 32 + khi * 4;
    if (EPI == 1) {
        ushort* ob = (ushort*)outp;
#pragma unroll
        for (int m = 0; m < 2; m++) {
#pragma unroll
            for (int jj = 0; jj < 4; jj++) {
                int r = rowbase + m * 16 + jj;
                if (r < mreal) {
                    float ns = nsrc[r];
#pragma unroll
                    for (int nn = 0; nn < 4; nn++) {
                        int col = colbase + nn * 16 + r16;
                        float v = acc[m][nn][jj] + bias[col] + feats[(size_t)r * DIM + col];
                        ob[(size_t)r * DIM + col] = f2bf(v * ns);
                    }
                }
            }
        }
    } else {
        uint8_t* o8 = (uint8_t*)outp;
#pragma unroll
        for (int m = 0; m < 2; m++) {
#pragma unroll
            for (int jj = 0; jj < 4; jj++) {
                int r = rowbase + m * 16 + jj;
                if (r < mreal) {
#pragma unroll
                    for (int nn = 0; nn < 4; nn++) {
                        int col = colbase + nn * 16 + r16;
                        o8[(size_t)r * DIM + col] = f2fp8(acc[m][nn][jj] * 16.f);
                    }
                }
            }
        }
    }
}

// ---------------- fused aggregation + bias + relu + wnode column-reduction (fp8 z) ----------
// vec[c] += sum_v wnode[v] * relu( ndst[v]/16 * sum_{e:dst=v} z8[src_e][c] + b_g1[c] )
// z8 rows are 1024 B; lane owns 16 consecutive byte-cols -> one dwordx4 gather per edge.

__global__ __launch_bounds__(256) void agg2_kernel(
    const uint8_t* __restrict__ z8, const int* __restrict__ row_ptr,
    const int* __restrict__ in_deg, const int* __restrict__ csr_src,
    const float* __restrict__ ndst, const float* __restrict__ wnode,
    const float* __restrict__ bg1, float* __restrict__ vec, int n) {
    __shared__ float red[DIM];
    int lane = threadIdx.x & 63, wid = threadIdx.x >> 6;
    int wave = blockIdx.x * 4 + wid;
    int nwaves = gridDim.x * 4;
    int c0 = lane * 16;  // byte col base; thread owns cols [c0, c0+16)

    float bv[16];
#pragma unroll
    for (int t = 0; t < 16; t++) bv[t] = bg1[c0 + t];
    float part[16];
#pragma unroll
    for (int t = 0; t < 16; t++) part[t] = 0.f;

    for (int node = wave; node < n; node += nwaves) {
        int start = row_ptr[node], cnt = in_deg[node];
        float a[16];
#pragma unroll
        for (int t = 0; t < 16; t++) a[t] = 0.f;
        int e = 0;
        for (; e + 8 <= cnt; e += 8) {  // 8-edge unroll: 8 gather loads in flight
            uint4 v[8];
#pragma unroll
            for (int q = 0; q < 8; q++)
                v[q] = *(const uint4*)(z8 + (size_t)csr_src[start + e + q] * DIM + c0);
#pragma unroll
            for (int q = 0; q < 8; q++) {
                acc_fp8x4(v[q].x, a + 0);
                acc_fp8x4(v[q].y, a + 4);
                acc_fp8x4(v[q].z, a + 8);
                acc_fp8x4(v[q].w, a + 12);
            }
        }
        for (; e < cnt; e++) {
            uint4 v0 = *(const uint4*)(z8 + (size_t)csr_src[start + e] * DIM + c0);
            acc_fp8x4(v0.x, a + 0);
            acc_fp8x4(v0.y, a + 4);
            acc_fp8x4(v0.z, a + 8);
            acc_fp8x4(v0.w, a + 12);
        }
        float nd16 = ndst[node] * 0.0625f, w = wnode[node];
#pragma unroll
        for (int t = 0; t < 16; t++)
            part[t] = fmaf(w, fmaxf(fmaf(nd16, a[t], bv[t]), 0.f), part[t]);
    }

    // block reduce across the 4 waves (same lane->col mapping) then one atomic pass
    if (wid == 0) {
#pragma unroll
        for (int t = 0; t < 16; t++) red[c0 + t] = part[t];
    }
    __syncthreads();
    for (int w = 1; w < 4; ++w) {
        if (wid == w) {
#pragma unroll
            for (int t = 0; t < 16; t++) red[c0 + t] += part[t];
        }
        __syncthreads();
    }
    for (int c = threadIdx.x; c < DIM; c += 256) atomicAdd(&vec[c], red[c]);
}

// ---------------- final GEMV: out = (1/N)*vec @ w_g2 + b_g2 ----------------

__global__ __launch_bounds__(256) void final_kernel(const float* __restrict__ vec,
                                                    const float* __restrict__ w2,
                                                    const float* __restrict__ b2,
                                                    float* out, float invn) {
    int d = blockIdx.x * 256 + threadIdx.x;
    int kb = blockIdx.y * 128;
    float acc = 0.f;
#pragma unroll 4
    for (int k = 0; k < 128; k++) acc = fmaf(vec[kb + k], w2[(size_t)(kb + k) * DIM + d], acc);
    float add = acc * invn + (blockIdx.y == 0 ? b2[d] : 0.f);
    atomicAdd(&out[d], add);
}

// ---------------- launch ----------------

extern "C" void kernel_launch(void* const* d_in, const int* in_sizes, int n_in,
                              void* d_out, int out_size, void* d_ws, size_t ws_size,
                              hipStream_t stream) {
    const float* feats  = (const float*)d_in[0];
    const float* boxes  = (const float*)d_in[1];
    const int*   esrc   = (const int*)d_in[2];
    const int*   edst   = (const int*)d_in[3];
    const float* w_pos1 = (const float*)d_in[4];
    const float* b_pos1 = (const float*)d_in[5];
    const float* w_pos2 = (const float*)d_in[6];
    const float* b_pos2 = (const float*)d_in[7];
    const float* w_g1   = (const float*)d_in[8];
    const float* b_g1   = (const float*)d_in[9];
    const float* w_g2   = (const float*)d_in[10];
    const float* b_g2   = (const float*)d_in[11];

    int n = in_sizes[0] / DIM;   // 20000
    int ee = in_sizes[2];        // 180000
    int mtiles = (n + 127) / 128;
    int groups = (mtiles + 7) / 8;
    int gemm_grid = groups * 64;     // 8 xcd * 8 bn * groups

    char* p = (char*)d_ws;
    auto alloc = [&](size_t bytes) -> char* {
        char* r = p;
        p += (bytes + 255) & ~((size_t)255);
        return r;
    };
    size_t mp = (size_t)mtiles * 128;
    ushort* t_z    = (ushort*)alloc(mp * DIM * 2);  // t (bf16), later reused as z (fp8)
    ushort* hs     = (ushort*)alloc(mp * DIM * 2);
    ushort* wt1    = (ushort*)alloc((size_t)DIM * DIM * 2);  // w_pos2^T bf16
    ushort* wt2    = (ushort*)alloc((size_t)DIM * DIM * 2);  // w_g1^T bf16
    char* zero_base = p;
    int*   out_deg = (int*)alloc((size_t)n * 4);
    int*   in_deg  = (int*)alloc((size_t)n * 4);
    float* cw      = (float*)alloc((size_t)n * 4);   // c, then w_node in place
    float* vec     = (float*)alloc((size_t)DIM * 4);
    size_t zero_bytes = (size_t)(p - zero_base);
    float* nsrc    = (float*)alloc((size_t)n * 4);
    float* ndst    = (float*)alloc((size_t)n * 4);
    int*   row_ptr = (int*)alloc((size_t)(n + 1) * 4);
    int*   cursor  = (int*)alloc((size_t)n * 4);
    int*   csr_src = (int*)alloc((size_t)ee * 4);

    hipMemsetAsync(zero_base, 0, zero_bytes, stream);
    hipMemsetAsync(d_out, 0, (size_t)out_size * 4, stream);

    int eb = (ee + 255) / 256;
    int nb = (n + 255) / 256;

    deg_kernel<<<eb, 256, 0, stream>>>(esrc, edst, out_deg, in_deg, ee);
    posA_kernel<<<256, 256, 0, stream>>>(boxes, w_pos1, b_pos1, t_z, n);
    transpose_bf16_kernel<<<dim3(32, 32), 256, 0, stream>>>(w_pos2, wt1);
    transpose_bf16_kernel<<<dim3(32, 32), 256, 0, stream>>>(w_g1, wt2);
    norm_kernel<<<nb, 256, 0, stream>>>(out_deg, in_deg, nsrc, ndst, n);
    csum_kernel<<<eb, 256, 0, stream>>>(esrc, edst, ndst, cw, ee);
    scan_kernel<<<1, 1024, 0, stream>>>(in_deg, row_ptr, cursor, n);
    wnode_kernel<<<nb, 256, 0, stream>>>(cw, nsrc, n);
    scatter_kernel<<<eb, 256, 0, stream>>>(esrc, edst, cursor, csr_src, ee);

    // GEMM1: hs = bf16((t @ w_pos2 + b_pos2 + feats) * norm_src)
    gemm_kernel<1><<<gemm_grid, 512, 0, stream>>>(t_z, wt1, b_pos2, feats, nsrc, (void*)hs,
                                                  mtiles, n);
    // GEMM2: z8 = fp8(16 * hs @ w_g1)   (t buffer dead -> reuse as z8)
    uint8_t* z8 = (uint8_t*)t_z;
    gemm_kernel<0><<<gemm_grid, 512, 0, stream>>>(hs, wt2, nullptr, nullptr, nullptr, (void*)z8,
                                                  mtiles, n);
    // fused aggregation + bias + relu + wnode reduction (fp8 gather)
    agg2_kernel<<<2048, 256, 0, stream>>>(z8, row_ptr, in_deg, csr_src, ndst, cw, b_g1, vec, n);
    final_kernel<<<dim3(4, 8), 256, 0, stream>>>(vec, w_g2, b_g2, (float*)d_out, 1.0f / (float)n);
}

// Round 11
// 419.314 us; speedup vs baseline: 1.8120x; 1.0117x over previous
//
#include <hip/hip_runtime.h>
#include <hip/hip_bf16.h>
#include <stdint.h>

#define DIM 1024

typedef __attribute__((ext_vector_type(4))) float f32x4;
typedef __attribute__((ext_vector_type(2))) float f32x2;
typedef __attribute__((ext_vector_type(8))) short short8;

__device__ __forceinline__ float bf2f(ushort u) {
    union { uint32_t u; float f; } c; c.u = ((uint32_t)u) << 16; return c.f;
}
__device__ __forceinline__ ushort f2bf(float f) {
    union { float f; uint32_t u; } c; c.f = f;
    uint32_t r = (c.u + 0x7fffu + ((c.u >> 16) & 1u)) >> 16;
    return (ushort)r;
}
// f32 -> fp8 e4m3 (OCP) via HW cvt; returns low byte.
__device__ __forceinline__ uint8_t f2fp8(float v) {
    int b;
    asm("v_cvt_pk_fp8_f32 %0, %1, %2" : "=v"(b) : "v"(v), "v"(v));
    return (uint8_t)b;
}
// 4 fp8 (one dword) -> accumulate into a[0..3]
__device__ __forceinline__ void acc_fp8x4(uint32_t dw, float* a) {
    f32x2 lo, hi;
    asm("v_cvt_pk_f32_fp8 %0, %1" : "=v"(lo) : "v"(dw));
    uint32_t dwh = dw >> 16;
    asm("v_cvt_pk_f32_fp8 %0, %1" : "=v"(hi) : "v"(dwh));
    a[0] += lo[0]; a[1] += lo[1]; a[2] += hi[0]; a[3] += hi[1];
}

// async global->LDS, 16B per lane. LDS dest is wave-uniform base (+lane*16 implicit).
__device__ __forceinline__ void async_copy16(void* lds, const void* g) {
    __builtin_amdgcn_global_load_lds((const __attribute__((address_space(1))) void*)g,
                                     (__attribute__((address_space(3))) void*)lds, 16, 0, 0);
}

// ---------------- fused prep: [0,1024) w_pos2^T, [1024,2048) w_g1^T, [2048,2304) posA,
// ----------------             [2304,2312) zero workspace counters + d_out ----------------

__device__ void transpose_tile(const float* __restrict__ w, ushort* __restrict__ wt,
                               int bx, int by, int tid) {
    __shared__ float tile[32][33];
    int tx = tid & 31, ty = tid >> 5;  // 32x8
#pragma unroll
    for (int r = 0; r < 32; r += 8)
        tile[ty + r][tx] = w[(size_t)(by * 32 + ty + r) * DIM + bx * 32 + tx];
    __syncthreads();
#pragma unroll
    for (int r = 0; r < 32; r += 8)
        wt[(size_t)(bx * 32 + ty + r) * DIM + by * 32 + tx] = f2bf(tile[tx][ty + r]);
}

__global__ __launch_bounds__(256) void prep_kernel(
    const float* __restrict__ w_pos2, ushort* __restrict__ wt1,
    const float* __restrict__ w_g1, ushort* __restrict__ wt2,
    const float* __restrict__ boxes, const float* __restrict__ w1,
    const float* __restrict__ b1, ushort* __restrict__ t, int n,
    float* __restrict__ zero_base, int zero_words,
    float* __restrict__ d_out, int out_words) {
    int bid = blockIdx.x, tid = threadIdx.x;
    if (bid < 1024) {
        transpose_tile(w_pos2, wt1, bid & 31, bid >> 5, tid);
    } else if (bid < 2048) {
        int b = bid - 1024;
        transpose_tile(w_g1, wt2, b & 31, b >> 5, tid);
    } else if (bid < 2304) {
        int pb = bid - 2048;  // 256 posA blocks
        int lane = tid & 63, wid = tid >> 6;
        int wave = pb * 4 + wid, nw = 1024;
        int c0 = lane * 16;
        for (int row = wave; row < n; row += nw) {
            float b[4];
#pragma unroll
            for (int j = 0; j < 4; j++) {
                float v = boxes[row * 4 + j];
                b[j] = fminf(fmaxf(v, -10.f), 10.f);
            }
            short8 o[2];
#pragma unroll
            for (int h = 0; h < 2; h++) {
#pragma unroll
                for (int q = 0; q < 8; q++) {
                    int col = c0 + h * 8 + q;
                    float v = b1[col];
#pragma unroll
                    for (int j = 0; j < 4; j++) v = fmaf(b[j], w1[j * DIM + col], v);
                    o[h][q] = (short)f2bf(fmaxf(v, 0.f));
                }
            }
            *(short8*)(t + (size_t)row * DIM + c0) = o[0];
            *(short8*)(t + (size_t)row * DIM + c0 + 8) = o[1];
        }
    } else {
        int zb = bid - 2304;  // 8 zero blocks, f32x4 grid-stride
        int i = (zb * 256 + tid) * 4;
        int stride = 8 * 256 * 4;
        for (; i + 3 < zero_words; i += stride)
            *(f32x4*)(zero_base + i) = (f32x4){0.f, 0.f, 0.f, 0.f};
        for (int d = zb * 256 + tid; d < out_words; d += 8 * 256) d_out[d] = 0.f;
    }
}

// ---------------- deg: edge-parallel degree atomics ----------------

__global__ void deg_kernel(const int* __restrict__ src, const int* __restrict__ dst,
                           int* out_deg, int* in_deg, int ee) {
    int e = blockIdx.x * 256 + threadIdx.x;
    if (e < ee) {
        atomicAdd(&out_deg[src[e]], 1);
        atomicAdd(&in_deg[dst[e]], 1);
    }
}

// ---------------- scan (single block): row_ptr/cursor = exscan(in_deg); ns, nd ----------------

__global__ void scan_kernel(const int* __restrict__ in_deg, const int* __restrict__ out_deg,
                            int* row_ptr, int* cursor, float* ns, float* nd, int n) {
    __shared__ int wsum[16];
    __shared__ int carry_s;
    int tid = threadIdx.x, lane = tid & 63, wid = tid >> 6;
    if (tid == 0) carry_s = 0;
    __syncthreads();
    for (int base = 0; base < n; base += 1024) {
        int x = (base + tid < n) ? in_deg[base + tid] : 0;
        int v = x;
#pragma unroll
        for (int off = 1; off < 64; off <<= 1) {
            int u = __shfl_up(v, off);
            if (lane >= off) v += u;
        }
        if (lane == 63) wsum[wid] = v;
        __syncthreads();
        if (wid == 0 && lane < 16) {
            int wv = wsum[lane];
#pragma unroll
            for (int off = 1; off < 16; off <<= 1) {
                int wu = __shfl_up(wv, off);
                if (lane >= off) wv += wu;
            }
            wsum[lane] = wv;
        }
        __syncthreads();
        int waveoff = (wid > 0) ? wsum[wid - 1] : 0;
        if (base + tid < n) {
            int i = base + tid;
            int ex = carry_s + waveoff + v - x;
            row_ptr[i] = ex;
            cursor[i] = ex;
            int od = out_deg[i];
            ns[i] = od > 0 ? rsqrtf((float)od) : 0.f;
            nd[i] = x > 0 ? rsqrtf((float)x) : 0.f;
        }
        __syncthreads();
        if (tid == 0) carry_s += wsum[15];
        __syncthreads();
    }
}

// ---------------- fused edge work: csum (cw[src] += nd[dst]) + CSR scatter ----------------

__global__ void edge_kernel(const int* __restrict__ src, const int* __restrict__ dst,
                            const float* __restrict__ nd, float* cw,
                            int* cursor, int* csr_src, int ee) {
    int e = blockIdx.x * 256 + threadIdx.x;
    if (e < ee) {
        int s = src[e], d = dst[e];
        atomicAdd(&cw[s], nd[d]);
        int p = atomicAdd(&cursor[d], 1);
        csr_src[p] = s;
    }
}

// ---------------- 128x128 bf16 MFMA GEMM, BK=64, 8 waves, counted-vmcnt dbuf (R5 struct) ----
// Grid: flat, XCD-grouped: j&7 = XCD, all 8 bn for a bm run consecutively on one XCD.
// EPI==0: outp = fp8_e4m3(C * 16)                         (rows < mreal)  [z path]
// EPI==1: outp = bf16((C + bias + feats) * nsrc[row])     (rows < mreal)  [hs path]

template <int EPI>
__global__ __launch_bounds__(512, 4) void gemm_kernel(
    const ushort* __restrict__ A, const ushort* __restrict__ Bt,
    const float* __restrict__ bias, const float* __restrict__ feats,
    const float* __restrict__ nsrc, void* __restrict__ outp,
    int mtiles, int mreal) {
    __shared__ __align__(128) ushort ldsA[2][128 * 64];
    __shared__ __align__(128) ushort ldsB[2][128 * 64];
    int j = blockIdx.x;
    int xcd = j & 7, kq = j >> 3;
    int bm = xcd + 8 * (kq >> 3);
    int bn = kq & 7;
    if (bm >= mtiles) return;

    int tid = threadIdx.x, lane = tid & 63, wid = tid >> 6;  // 8 waves
    int wm = wid >> 1, wn = wid & 1;  // 4x2 wave grid, each 32x64 output

    f32x4 acc[2][4];
#pragma unroll
    for (int m = 0; m < 2; m++)
#pragma unroll
        for (int nn = 0; nn < 4; nn++) acc[m][nn] = (f32x4){0.f, 0.f, 0.f, 0.f};

    // staging: wave w covers rows {w*8 + c*64} (8 rows per load), A and B -> 4 loads/wave/stage.
    // LDS linear [row][seg]; global source seg pre-XOR-swizzled (rule #21).
    int srow = wid * 8 + (lane >> 3);
    int sseg = (lane & 7) ^ (lane >> 3);
    const ushort* gA = A + (size_t)(bm * 128 + srow) * DIM + sseg * 8;
    const ushort* gB = Bt + (size_t)(bn * 128 + srow) * DIM + sseg * 8;
    int ldsoff0 = (wid * 8) * 64;

    int r16 = lane & 15, khi = lane >> 4;

    auto stage = [&](int buf, int kt) {
#pragma unroll
        for (int c = 0; c < 2; c++) {
            async_copy16(&ldsA[buf][ldsoff0 + c * 64 * 64], gA + (size_t)c * 64 * DIM + kt * 64);
            async_copy16(&ldsB[buf][ldsoff0 + c * 64 * 64], gB + (size_t)c * 64 * DIM + kt * 64);
        }
    };

    stage(0, 0);
    int cur = 0;
    for (int kt = 0; kt < DIM / 64; ++kt) {
        if (kt + 1 < DIM / 64) {
            stage(cur ^ 1, kt + 1);                         // 4 more loads in flight
            asm volatile("s_waitcnt vmcnt(4)" ::: "memory");  // only stage kt's 4 must land
        } else {
            asm volatile("s_waitcnt vmcnt(0)" ::: "memory");
        }
        __builtin_amdgcn_s_barrier();          // raw: does NOT drain the prefetch
        __builtin_amdgcn_sched_barrier(0);
#pragma unroll
        for (int kk = 0; kk < 2; kk++) {
            short8 af[2], bfv[4];
#pragma unroll
            for (int m = 0; m < 2; m++) {
                int row = wm * 32 + m * 16 + r16;
                int seg = (kk * 4 + khi) ^ (row & 7);
                af[m] = *(const short8*)&ldsA[cur][row * 64 + seg * 8];
            }
#pragma unroll
            for (int nn = 0; nn < 4; nn++) {
                int row = wn * 64 + nn * 16 + r16;
                int seg = (kk * 4 + khi) ^ (row & 7);
                bfv[nn] = *(const short8*)&ldsB[cur][row * 64 + seg * 8];
            }
#pragma unroll
            for (int m = 0; m < 2; m++)
#pragma unroll
                for (int nn = 0; nn < 4; nn++)
                    acc[m][nn] = __builtin_amdgcn_mfma_f32_16x16x32_bf16(af[m], bfv[nn], acc[m][nn], 0, 0, 0);
        }
        __builtin_amdgcn_sched_barrier(0);
        __builtin_amdgcn_s_barrier();          // all waves done reading buf before overwrite
        cur ^= 1;
    }

    // C/D mapping (m89): col = lane&15, row = (lane>>4)*4 + j
    int colbase = bn * 128 + wn * 64;
    int rowbase = bm * 128 + wm * 32 + khi * 4;
    if (EPI == 1) {
        ushort* ob = (ushort*)outp;
#pragma unroll
        for (int m = 0; m < 2; m++) {
#pragma unroll
            for (int jj = 0; jj < 4; jj++) {
                int r = rowbase + m * 16 + jj;
                if (r < mreal) {
                    float ns = nsrc[r];
#pragma unroll
                    for (int nn = 0; nn < 4; nn++) {
                        int col = colbase + nn * 16 + r16;
                        float v = acc[m][nn][jj] + bias[col] + feats[(size_t)r * DIM + col];
                        ob[(size_t)r * DIM + col] = f2bf(v * ns);
                    }
                }
            }
        }
    } else {
        uint8_t* o8 = (uint8_t*)outp;
#pragma unroll
        for (int m = 0; m < 2; m++) {
#pragma unroll
            for (int jj = 0; jj < 4; jj++) {
                int r = rowbase + m * 16 + jj;
                if (r < mreal) {
#pragma unroll
                    for (int nn = 0; nn < 4; nn++) {
                        int col = colbase + nn * 16 + r16;
                        o8[(size_t)r * DIM + col] = f2fp8(acc[m][nn][jj] * 16.f);
                    }
                }
            }
        }
    }
}

// ---------------- fused aggregation + bias + relu + wnode column-reduction (fp8 z) ----------
// vec[c] += sum_v (cw[v]*ns[v]) * relu( ndst[v]/16 * sum_{e:dst=v} z8[src_e][c] + b_g1[c] )

__global__ __launch_bounds__(256) void agg2_kernel(
    const uint8_t* __restrict__ z8, const int* __restrict__ row_ptr,
    const int* __restrict__ in_deg, const int* __restrict__ csr_src,
    const float* __restrict__ ndst, const float* __restrict__ cw,
    const float* __restrict__ ns, const float* __restrict__ bg1,
    float* __restrict__ vec, int n) {
    __shared__ float red[DIM];
    int lane = threadIdx.x & 63, wid = threadIdx.x >> 6;
    int wave = blockIdx.x * 4 + wid;
    int nwaves = gridDim.x * 4;
    int c0 = lane * 16;  // byte col base; thread owns cols [c0, c0+16)

    float bv[16];
#pragma unroll
    for (int t = 0; t < 16; t++) bv[t] = bg1[c0 + t];
    float part[16];
#pragma unroll
    for (int t = 0; t < 16; t++) part[t] = 0.f;

    for (int node = wave; node < n; node += nwaves) {
        int start = row_ptr[node], cnt = in_deg[node];
        float a[16];
#pragma unroll
        for (int t = 0; t < 16; t++) a[t] = 0.f;
        int e = 0;
        for (; e + 8 <= cnt; e += 8) {  // 8-edge unroll: 8 gather loads in flight
            uint4 v[8];
#pragma unroll
            for (int q = 0; q < 8; q++)
                v[q] = *(const uint4*)(z8 + (size_t)csr_src[start + e + q] * DIM + c0);
#pragma unroll
            for (int q = 0; q < 8; q++) {
                acc_fp8x4(v[q].x, a + 0);
                acc_fp8x4(v[q].y, a + 4);
                acc_fp8x4(v[q].z, a + 8);
                acc_fp8x4(v[q].w, a + 12);
            }
        }
        for (; e < cnt; e++) {
            uint4 v0 = *(const uint4*)(z8 + (size_t)csr_src[start + e] * DIM + c0);
            acc_fp8x4(v0.x, a + 0);
            acc_fp8x4(v0.y, a + 4);
            acc_fp8x4(v0.z, a + 8);
            acc_fp8x4(v0.w, a + 12);
        }
        float nd16 = ndst[node] * 0.0625f;
        float w = cw[node] * ns[node];   // wnode inline
#pragma unroll
        for (int t = 0; t < 16; t++)
            part[t] = fmaf(w, fmaxf(fmaf(nd16, a[t], bv[t]), 0.f), part[t]);
    }

    // block reduce across the 4 waves (same lane->col mapping) then one atomic pass
    if (wid == 0) {
#pragma unroll
        for (int t = 0; t < 16; t++) red[c0 + t] = part[t];
    }
    __syncthreads();
    for (int w = 1; w < 4; ++w) {
        if (wid == w) {
#pragma unroll
            for (int t = 0; t < 16; t++) red[c0 + t] += part[t];
        }
        __syncthreads();
    }
    for (int c = threadIdx.x; c < DIM; c += 256) atomicAdd(&vec[c], red[c]);
}

// ---------------- final GEMV: out = (1/N)*vec @ w_g2 + b_g2 ----------------

__global__ __launch_bounds__(256) void final_kernel(const float* __restrict__ vec,
                                                    const float* __restrict__ w2,
                                                    const float* __restrict__ b2,
                                                    float* out, float invn) {
    int d = blockIdx.x * 256 + threadIdx.x;
    int kb = blockIdx.y * 128;
    float acc = 0.f;
#pragma unroll 4
    for (int k = 0; k < 128; k++) acc = fmaf(vec[kb + k], w2[(size_t)(kb + k) * DIM + d], acc);
    float add = acc * invn + (blockIdx.y == 0 ? b2[d] : 0.f);
    atomicAdd(&out[d], add);
}

// ---------------- launch: 8 dispatches total ----------------

extern "C" void kernel_launch(void* const* d_in, const int* in_sizes, int n_in,
                              void* d_out, int out_size, void* d_ws, size_t ws_size,
                              hipStream_t stream) {
    const float* feats  = (const float*)d_in[0];
    const float* boxes  = (const float*)d_in[1];
    const int*   esrc   = (const int*)d_in[2];
    const int*   edst   = (const int*)d_in[3];
    const float* w_pos1 = (const float*)d_in[4];
    const float* b_pos1 = (const float*)d_in[5];
    const float* w_pos2 = (const float*)d_in[6];
    const float* b_pos2 = (const float*)d_in[7];
    const float* w_g1   = (const float*)d_in[8];
    const float* b_g1   = (const float*)d_in[9];
    const float* w_g2   = (const float*)d_in[10];
    const float* b_g2   = (const float*)d_in[11];

    int n = in_sizes[0] / DIM;   // 20000
    int ee = in_sizes[2];        // 180000
    int mtiles = (n + 127) / 128;
    int groups = (mtiles + 7) / 8;
    int gemm_grid = groups * 64;     // 8 xcd * 8 bn * groups

    char* p = (char*)d_ws;
    auto alloc = [&](size_t bytes) -> char* {
        char* r = p;
        p += (bytes + 255) & ~((size_t)255);
        return r;
    };
    size_t mp = (size_t)mtiles * 128;
    ushort* t_z    = (ushort*)alloc(mp * DIM * 2);  // t (bf16), later reused as z (fp8)
    ushort* hs     = (ushort*)alloc(mp * DIM * 2);
    ushort* wt1    = (ushort*)alloc((size_t)DIM * DIM * 2);  // w_pos2^T bf16
    ushort* wt2    = (ushort*)alloc((size_t)DIM * DIM * 2);  // w_g1^T bf16
    char* zero_base = p;
    int*   out_deg = (int*)alloc((size_t)n * 4);
    int*   in_deg  = (int*)alloc((size_t)n * 4);
    float* cw      = (float*)alloc((size_t)n * 4);   // c; w = cw*ns computed inline in agg2
    float* vec     = (float*)alloc((size_t)DIM * 4);
    size_t zero_bytes = (size_t)(p - zero_base);
    float* nsrc    = (float*)alloc((size_t)n * 4);
    float* ndst    = (float*)alloc((size_t)n * 4);
    int*   row_ptr = (int*)alloc((size_t)(n + 1) * 4);
    int*   cursor  = (int*)alloc((size_t)n * 4);
    int*   csr_src = (int*)alloc((size_t)ee * 4);

    int eb = (ee + 255) / 256;

    // 1. prep: transposes + posA + zero(out_deg,in_deg,cw,vec) + zero(d_out)
    prep_kernel<<<2312, 256, 0, stream>>>(w_pos2, wt1, w_g1, wt2, boxes, w_pos1, b_pos1,
                                          t_z, n, (float*)zero_base, (int)(zero_bytes / 4),
                                          (float*)d_out, out_size);
    // 2. degrees
    deg_kernel<<<eb, 256, 0, stream>>>(esrc, edst, out_deg, in_deg, ee);
    // 3. scan + norms
    scan_kernel<<<1, 1024, 0, stream>>>(in_deg, out_deg, row_ptr, cursor, nsrc, ndst, n);
    // 4. edge work: csum + CSR scatter
    edge_kernel<<<eb, 256, 0, stream>>>(esrc, edst, ndst, cw, cursor, csr_src, ee);
    // 5. GEMM1: hs = bf16((t @ w_pos2 + b_pos2 + feats) * norm_src)
    gemm_kernel<1><<<gemm_grid, 512, 0, stream>>>(t_z, wt1, b_pos2, feats, nsrc, (void*)hs,
                                                  mtiles, n);
    // 6. GEMM2: z8 = fp8(16 * hs @ w_g1)   (t buffer dead -> reuse as z8)
    uint8_t* z8 = (uint8_t*)t_z;
    gemm_kernel<0><<<gemm_grid, 512, 0, stream>>>(hs, wt2, nullptr, nullptr, nullptr, (void*)z8,
                                                  mtiles, n);
    // 7. fused aggregation + bias + relu + wnode reduction (fp8 gather)
    agg2_kernel<<<2048, 256, 0, stream>>>(z8, row_ptr, in_deg, csr_src, ndst, cw, nsrc,
                                          b_g1, vec, n);
    // 8. final GEMV
    final_kernel<<<dim3(4, 8), 256, 0, stream>>>(vec, w_g2, b_g2, (float*)d_out, 1.0f / (float)n);
}